// Round 5
// baseline (84.657 us; speedup 1.0000x reference)
//
#include <hip/hip_runtime.h>

typedef unsigned int   u32;
typedef unsigned short u16;
typedef __bf16 bf16x8 __attribute__((ext_vector_type(8)));
typedef float  f32x4  __attribute__((ext_vector_type(4)));
typedef float  f32x16 __attribute__((ext_vector_type(16)));

__device__ __forceinline__ u16 f2b(float f) {
  u32 u = __float_as_uint(f);
  u = (u + 0x7fffu + ((u >> 16) & 1u)) >> 16;   // RNE
  return (u16)u;
}
__device__ __forceinline__ float b2f_lo(u32 u) { return __uint_as_float(u << 16); }
__device__ __forceinline__ float b2f_hi(u32 u) { return __uint_as_float(u & 0xffff0000u); }
__device__ __forceinline__ float silu_f(float x) { return __fdividef(x, 1.f + __expf(-x)); }

__device__ __forceinline__ float dot8(uint4 q, uint4 k, float acc) {
  acc += b2f_lo(q.x) * b2f_lo(k.x) + b2f_hi(q.x) * b2f_hi(k.x);
  acc += b2f_lo(q.y) * b2f_lo(k.y) + b2f_hi(q.y) * b2f_hi(k.y);
  acc += b2f_lo(q.z) * b2f_lo(k.z) + b2f_hi(q.z) * b2f_hi(k.z);
  acc += b2f_lo(q.w) * b2f_lo(k.w) + b2f_hi(q.w) * b2f_hi(k.w);
  return acc;
}

// ---------- prep (merged): blocks 0..63 transpose Wk/Wq; block 64 builds MLP tables ----------
// W0A/W1A: 32x32x16 A-frags (lane l: row=l&31, k-slot=8*(l>>5)+e).
// W1A k-slots permuted by sigma so layer-0 C-output packs directly as layer-1 B-frag.
// BT[t][0..7]=b0[j(e,hf)], [8..15]=b1[j], [16..23]=W2[j]  (j=(e&3)+8*(e>>2)+4*hf), stride 32.
__global__ __launch_bounds__(512) void prep_all(
    const float* __restrict__ Wk, const float* __restrict__ Wq,
    const float* __restrict__ W0, const float* __restrict__ W1,
    const float* __restrict__ b0, const float* __restrict__ b1,
    const float* __restrict__ W2,
    u16* __restrict__ Wkt, u16* __restrict__ Wqt,
    u16* __restrict__ W0A, u16* __restrict__ W1A, float* __restrict__ BT) {
  const int blk = blockIdx.x, t = threadIdx.x;
  if (blk < 64) {
    for (int idx = blk * 512 + t; idx < 65536; idx += 64 * 512) {
      int n = idx >> 8, k = idx & 255;
      Wkt[idx] = f2b(Wk[k * 256 + n]);
      Wqt[idx] = f2b(Wq[k * 256 + n]);
    }
  } else {
    const int h = t >> 6, l = t & 63;
    const int hf = l >> 5, j = l & 31;
    #pragma unroll
    for (int e = 0; e < 8; e++) {
      int k = 8 * hf + e;
      float v0 = (j < 16 && k < 10) ? W0[h * 160 + k * 16 + j] : 0.f;
      W0A[t * 8 + e] = f2b(v0);
      int jin = (k & 3) + 8 * ((k >> 2) & 1) + 4 * (k >> 3);  // sigma(k)
      float v1 = (j < 16) ? W1[h * 256 + jin * 16 + j] : 0.f;
      W1A[t * 8 + e] = f2b(v1);
      int cj = (e & 3) + 8 * (e >> 2) + 4 * hf;
      BT[t * 32 + e]      = b0[h * 16 + cj];
      BT[t * 32 + 8 + e]  = b1[h * 16 + cj];
      BT[t * 32 + 16 + e] = W2[h * 16 + cj];
    }
  }
}

// ---------- GEMM: C_bf16[8192][256] = A_f32[8192][256] @ W + bias (verified r3/r4) ----------
#define LDA 72
__global__ __launch_bounds__(256) void gemm_proj(
    const float* __restrict__ A0, const float* __restrict__ A1,
    const u16* __restrict__ B0, const u16* __restrict__ B1,
    const float* __restrict__ bias0, const float* __restrict__ bias1,
    u16* __restrict__ C0, u16* __restrict__ C1) {
  const float* A; const u16* Bt; const float* bias; u16* C;
  if (blockIdx.z == 0) { A = A0; Bt = B0; bias = bias0; C = C0; }
  else                 { A = A1; Bt = B1; bias = bias1; C = C1; }
  __shared__ __align__(16) u16 As[128 * LDA];
  __shared__ __align__(16) u16 Bs[128 * LDA];
  const int t = threadIdx.x;
  const int w = t >> 6, lane = t & 63;
  const int wm = w >> 1, wn = w & 1;
  const int row0 = blockIdx.x * 128, col0 = blockIdx.y * 128;
  f32x4 acc[4][4] = {};
  for (int kk = 0; kk < 256; kk += 64) {
    #pragma unroll
    for (int p = 0; p < 8; p++) {
      int r = p * 16 + (t >> 4), q = (t & 15) * 4;
      float4 v = *(const float4*)(A + (size_t)(row0 + r) * 256 + kk + q);
      uint2 pk;
      pk.x = (u32)f2b(v.x) | ((u32)f2b(v.y) << 16);
      pk.y = (u32)f2b(v.z) | ((u32)f2b(v.w) << 16);
      *(uint2*)(&As[r * LDA + q]) = pk;
    }
    #pragma unroll
    for (int p = 0; p < 4; p++) {
      int r = p * 32 + (t >> 3), q = (t & 7) * 8;
      *(uint4*)(&Bs[r * LDA + q]) = *(const uint4*)(Bt + (size_t)(col0 + r) * 256 + kk + q);
    }
    __syncthreads();
    #pragma unroll
    for (int ks = 0; ks < 2; ks++) {
      bf16x8 af[4], bfr[4];
      #pragma unroll
      for (int i = 0; i < 4; i++) {
        af[i]  = *(const bf16x8*)(&As[(wm * 64 + i * 16 + (lane & 15)) * LDA + ks * 32 + (lane >> 4) * 8]);
        bfr[i] = *(const bf16x8*)(&Bs[(wn * 64 + i * 16 + (lane & 15)) * LDA + ks * 32 + (lane >> 4) * 8]);
      }
      #pragma unroll
      for (int i = 0; i < 4; i++)
        #pragma unroll
        for (int j = 0; j < 4; j++)
          acc[i][j] = __builtin_amdgcn_mfma_f32_16x16x32_bf16(af[i], bfr[j], acc[i][j], 0, 0, 0);
    }
    __syncthreads();
  }
  #pragma unroll
  for (int j = 0; j < 4; j++) {
    int c = col0 + wn * 64 + j * 16 + (lane & 15);
    float bv = bias[c];
    #pragma unroll
    for (int i = 0; i < 4; i++) {
      int r0 = row0 + wm * 64 + i * 16 + (lane >> 4) * 4;
      #pragma unroll
      for (int q = 0; q < 4; q++)
        C[(size_t)(r0 + q) * 256 + c] = f2b(acc[i][j][q] + bv);
    }
  }
}

// ---------- fused v3: 2 n per block; gather+dot (VALU) + MLP (MFMA) ----------
// grid = B*N/2 = 4096; block = 512 = 8 waves; wave = head; lane = (hf, m)
__global__ __launch_bounds__(512) void fused_main(
    const u16* __restrict__ Kbf, const u16* __restrict__ Qbf,
    const int* __restrict__ nidx, const float* __restrict__ g,
    const u16* __restrict__ W0A, const u16* __restrict__ W1A,
    const float* __restrict__ BT, const float* __restrict__ b2,
    float* __restrict__ out) {
  __shared__ float lout[512];
  const int t = threadIdx.x;
  const int h = t >> 6, lane = t & 63;
  const int hf = lane >> 5, m = lane & 31;
  const int bn0 = blockIdx.x * 2;
  const int b = bn0 >> 12;
  const int hs = __builtin_amdgcn_readfirstlane(h);

  // per-thread constants (amortized over 2 outputs)
  const bf16x8 a0 = *(const bf16x8*)(W0A + (size_t)(hs * 64 + lane) * 8);
  const bf16x8 a1 = *(const bf16x8*)(W1A + (size_t)(hs * 64 + lane) * 8);
  const float4* btp = (const float4*)(BT + (size_t)t * 32);
  const float4 t0 = btp[0], t1 = btp[1], t2 = btp[2], t3 = btp[3], t4 = btp[4], t5 = btp[5];
  const float bj0[8] = {t0.x, t0.y, t0.z, t0.w, t1.x, t1.y, t1.z, t1.w};
  const float bj1[8] = {t2.x, t2.y, t2.z, t2.w, t3.x, t3.y, t3.z, t3.w};
  const float wj[8]  = {t4.x, t4.y, t4.z, t4.w, t5.x, t5.y, t5.z, t5.w};
  const float b2s = b2[hs];

  const int row0 = bn0 * 32 + m;
  const int i0 = nidx[row0], i1 = nidx[row0 + 32];

  // g loads, both n
  const float* gp0 = g + (size_t)row0 * 10;
  const float* gp1 = gp0 + 320;
  float2 gA0 = *(const float2*)(gp0 + hf * 8);
  float2 gB0 = *(const float2*)(gp1 + hf * 8);
  float2 gA1 = {0.f, 0.f}, gA2 = gA1, gA3 = gA1, gB1 = gA1, gB2 = gA1, gB3 = gA1;
  if (hf == 0) {
    gA1 = *(const float2*)(gp0 + 2); gA2 = *(const float2*)(gp0 + 4); gA3 = *(const float2*)(gp0 + 6);
    gB1 = *(const float2*)(gp1 + 2); gB2 = *(const float2*)(gp1 + 4); gB3 = *(const float2*)(gp1 + 6);
  }

  // Q/K loads, both n
  const uint4* qp0 = (const uint4*)(Qbf + (size_t)bn0 * 256 + h * 32 + hf * 16);
  const uint4* qp1 = (const uint4*)(Qbf + (size_t)(bn0 + 1) * 256 + h * 32 + hf * 16);
  const uint4* kp0 = (const uint4*)(Kbf + ((size_t)b * 4096 + i0) * 256 + h * 32 + hf * 16);
  const uint4* kp1 = (const uint4*)(Kbf + ((size_t)b * 4096 + i1) * 256 + h * 32 + hf * 16);
  uint4 qA0 = qp0[0], qA1 = qp0[1], kA0 = kp0[0], kA1 = kp0[1];
  uint4 qB0 = qp1[0], qB1 = qp1[1], kB0 = kp1[0], kB1 = kp1[1];

  float d0 = dot8(qA1, kA1, dot8(qA0, kA0, 0.f));
  float d1 = dot8(qB1, kB1, dot8(qB0, kB0, 0.f));

  // g B-fragments
  bf16x8 gf0, gf1;
  gf0[0] = (__bf16)gA0.x; gf0[1] = (__bf16)gA0.y; gf0[2] = (__bf16)gA1.x; gf0[3] = (__bf16)gA1.y;
  gf0[4] = (__bf16)gA2.x; gf0[5] = (__bf16)gA2.y; gf0[6] = (__bf16)gA3.x; gf0[7] = (__bf16)gA3.y;
  gf1[0] = (__bf16)gB0.x; gf1[1] = (__bf16)gB0.y; gf1[2] = (__bf16)gB1.x; gf1[3] = (__bf16)gB1.y;
  gf1[4] = (__bf16)gB2.x; gf1[5] = (__bf16)gB2.y; gf1[6] = (__bf16)gB3.x; gf1[7] = (__bf16)gB3.y;

  const f32x16 z = {};

  // ---- n0 ----
  f32x16 acc = __builtin_amdgcn_mfma_f32_32x32x16_bf16(a0, gf0, z, 0, 0, 0);
  bf16x8 h0b;
  #pragma unroll
  for (int e = 0; e < 8; e++) h0b[e] = (__bf16)silu_f(acc[e] + bj0[e]);
  acc = __builtin_amdgcn_mfma_f32_32x32x16_bf16(a1, h0b, z, 0, 0, 0);
  float p0 = 0.f;
  #pragma unroll
  for (int e = 0; e < 8; e++) p0 += silu_f(acc[e] + bj1[e]) * wj[e];

  // ---- n1 ----
  acc = __builtin_amdgcn_mfma_f32_32x32x16_bf16(a0, gf1, z, 0, 0, 0);
  #pragma unroll
  for (int e = 0; e < 8; e++) h0b[e] = (__bf16)silu_f(acc[e] + bj0[e]);
  acc = __builtin_amdgcn_mfma_f32_32x32x16_bf16(a1, h0b, z, 0, 0, 0);
  float p1 = 0.f;
  #pragma unroll
  for (int e = 0; e < 8; e++) p1 += silu_f(acc[e] + bj1[e]) * wj[e];

  // ---- combine halves + final ----
  float o0 = p0 + __shfl_xor(p0, 32, 64);
  float o1 = p1 + __shfl_xor(p1, 32, 64);
  float f0 = (d0 + __shfl_xor(d0, 32, 64)) * 0.17677669529663687f;
  float f1 = (d1 + __shfl_xor(d1, 32, 64)) * 0.17677669529663687f;
  float res0 = f0 + silu_f(o0 + b2s);
  float res1 = f1 + silu_f(o1 + b2s);

  if (hf == 0) {
    lout[m * 8 + h]       = res0;
    lout[256 + m * 8 + h] = res1;
  }
  __syncthreads();
  if (t < 128) {
    float4 v = ((const float4*)lout)[t];
    ((float4*)(out + (size_t)bn0 * 256))[t] = v;
  }
}

extern "C" void kernel_launch(void* const* d_in, const int* in_sizes, int n_in,
                              void* d_out, int out_size, void* d_ws, size_t ws_size,
                              hipStream_t stream) {
  const float* g_in = (const float*)d_in[0];
  // d_in[1] = nbhd_mask: unused by the reference
  const float* kf   = (const float*)d_in[2];
  const float* qf   = (const float*)d_in[3];
  const int*   idx  = (const int*)d_in[4];
  const float* Wk   = (const float*)d_in[5];
  const float* bk   = (const float*)d_in[6];
  const float* Wq   = (const float*)d_in[7];
  const float* bq   = (const float*)d_in[8];
  const float* W0   = (const float*)d_in[9];
  const float* b0   = (const float*)d_in[10];
  const float* W1   = (const float*)d_in[11];
  const float* b1   = (const float*)d_in[12];
  const float* W2   = (const float*)d_in[13];
  const float* b2   = (const float*)d_in[14];

  char* ws = (char*)d_ws;
  u16*   Kbf = (u16*)ws;                                        // 4 MB
  u16*   Qbf = (u16*)(ws + 4u * 1024 * 1024);                   // 4 MB
  u16*   Wkt = (u16*)(ws + 8u * 1024 * 1024);                   // 128 KB
  u16*   Wqt = (u16*)(ws + 8u * 1024 * 1024 + 131072);          // 128 KB
  u16*   W0A = (u16*)(ws + 8u * 1024 * 1024 + 262144);          // 8 KB
  u16*   W1A = (u16*)(ws + 8u * 1024 * 1024 + 262144 + 8192);   // 8 KB
  float* BT  = (float*)(ws + 8u * 1024 * 1024 + 262144 + 16384);// 64 KB

  prep_all<<<65, 512, 0, stream>>>(Wk, Wq, W0, W1, b0, b1, W2, Wkt, Wqt, W0A, W1A, BT);
  gemm_proj<<<dim3(64, 2, 2), 256, 0, stream>>>(kf, qf, Wkt, Wqt, bk, bq, Kbf, Qbf);
  fused_main<<<4096, 512, 0, stream>>>(Kbf, Qbf, idx, g_in, W0A, W1A, BT, b2,
                                       (float*)d_out);
}